// Round 3
// baseline (349.115 us; speedup 1.0000x reference)
//
#include <hip/hip_runtime.h>

#define BB 16
#define ENC 64
#define HH 96
#define EE 128
#define VV 32000

__device__ __forceinline__ float tanh_fast(float x) {
    float e = __expf(2.f * x);
    return 1.f - 2.f / (e + 1.f);
}
__device__ __forceinline__ float sigmoid_fast(float x) {
    return 1.f / (1.f + __expf(-x));
}
// round-to-nearest-even bf16 pack: low16 <- a, high16 <- b
__device__ __forceinline__ unsigned bf16pack(float a, float b) {
    unsigned ua = __float_as_uint(a);
    ua += 0x7FFFu + ((ua >> 16) & 1u);
    unsigned ub = __float_as_uint(b);
    ub += 0x7FFFu + ((ub >> 16) & 1u);
    return (ua >> 16) | (ub & 0xFFFF0000u);
}
#define BF_LO(u) __uint_as_float((u) << 16)
#define BF_HI(u) __uint_as_float((u) & 0xFFFF0000u)

// ---------------------------------------------------------------------------
// K0: partial enc_feat -> bf16. part[ic][b][o][x] = sum_{i in chunk, kw}
//     attn_w[o,i,47,kw] * encpad[b,i,x+kw].
// grid 1024 = b(16) * otile(4; 16 o) * ichunk(16; 4 i), 128 threads (2 waves).
// Lane tile: 1 o-row x 12 x. Rolling 4xfloat4 E window; conflict-free banks.
// ---------------------------------------------------------------------------
#define STEP(q, wa, wb_, wc_, wd_) do { \
    accA.x += q.x*wa.x  + q.y*wa.y  + q.z*wa.z  + q.w*wa.w;  \
    accA.y += q.x*wa.y  + q.y*wa.z  + q.z*wa.w  + q.w*wb_.x; \
    accA.z += q.x*wa.z  + q.y*wa.w  + q.z*wb_.x + q.w*wb_.y; \
    accA.w += q.x*wa.w  + q.y*wb_.x + q.z*wb_.y + q.w*wb_.z; \
    accB.x += q.x*wb_.x + q.y*wb_.y + q.z*wb_.z + q.w*wb_.w; \
    accB.y += q.x*wb_.y + q.y*wb_.z + q.z*wb_.w + q.w*wc_.x; \
    accB.z += q.x*wb_.z + q.y*wb_.w + q.z*wc_.x + q.w*wc_.y; \
    accB.w += q.x*wb_.w + q.y*wc_.x + q.z*wc_.y + q.w*wc_.z; \
    accC.x += q.x*wc_.x + q.y*wc_.y + q.z*wc_.z + q.w*wc_.w; \
    accC.y += q.x*wc_.y + q.y*wc_.z + q.z*wc_.w + q.w*wd_.x; \
    accC.z += q.x*wc_.z + q.y*wc_.w + q.z*wd_.x + q.w*wd_.y; \
    accC.w += q.x*wc_.w + q.y*wd_.x + q.z*wd_.y + q.w*wd_.z; \
} while (0)

__global__ __launch_bounds__(128) void k_encfeat(
    const float* __restrict__ enc,      // (B,ENC,H)
    const float* __restrict__ attn_w,   // (ENC,ENC,H,H)
    const float* __restrict__ cvg_w,    // (ENC,ENC,1,H)
    unsigned short* __restrict__ part,  // (16,B,ENC,H) bf16 partial sums
    float* __restrict__ cvgw47)         // (ENC,ENC)
{
    int blk = blockIdx.x;
    int b   = blk >> 6;          // 16
    int ot  = (blk >> 4) & 3;    // 4  (16 o each)
    int ic  = blk & 15;          // 16 (4 i each)
    int o0  = ot * 16;
    int i0  = ic * 4;
    int t   = threadIdx.x;

    __shared__ __align__(16) float encS[4 * 208];      // [47 zero | 96 enc | 65 zero]
    __shared__ __align__(16) float Wb[4 * 16 * 100];   // [i][o16][k], stride 100

    for (int f = t; f < 208; f += 128)
        ((float4*)encS)[f] = make_float4(0.f, 0.f, 0.f, 0.f);
    __syncthreads();
    for (int f = t; f < 4 * 96; f += 128) {
        int i = f / 96, j = f - i * 96;
        encS[i * 208 + 47 + j] = enc[(size_t)((b * ENC + i0 + i) * 96) + j];
    }
    for (int F = t; F < 1536; F += 128) {
        int o = F / 96;
        int r = F - o * 96;
        int i = r / 24, kq = r - i * 24;
        float4 q = *(const float4*)(attn_w +
            (size_t)((o0 + o) * ENC + (i0 + i)) * (96 * 96) + 47 * 96 + 4 * kq);
        *(float4*)&Wb[(i * 16 + o) * 100 + 4 * kq] = q;
    }
    if (b == 0 && ot == 0 && ic < 8) {
        #pragma unroll
        for (int j = 0; j < 4; ++j) {
            int e = ic * 512 + j * 128 + t;
            cvgw47[e] = cvg_w[(size_t)e * 96 + 47];
        }
    }
    __syncthreads();

    int w    = t >> 6;
    int ln   = t & 63;
    int og   = ln & 7;
    int xs   = ln >> 3;
    int x0   = xs * 12;
    int orow = w * 8 + og;

    float4 accA = make_float4(0.f, 0.f, 0.f, 0.f);
    float4 accB = make_float4(0.f, 0.f, 0.f, 0.f);
    float4 accC = make_float4(0.f, 0.f, 0.f, 0.f);

    for (int i = 0; i < 4; ++i) {
        const float* er = &encS[i * 208 + x0];
        const float* wr = &Wb[(i * 16 + orow) * 100];
        float4 e0 = *(const float4*)(er);
        float4 e1 = *(const float4*)(er + 4);
        float4 e2 = *(const float4*)(er + 8);
        float4 e3 = *(const float4*)(er + 12);
        #pragma unroll
        for (int cb = 0; cb < 6; ++cb) {
            float4 q0 = *(const float4*)(wr + 16 * cb);
            float4 q1 = *(const float4*)(wr + 16 * cb + 4);
            float4 q2 = *(const float4*)(wr + 16 * cb + 8);
            float4 q3 = *(const float4*)(wr + 16 * cb + 12);
            STEP(q0, e0, e1, e2, e3);
            e0 = *(const float4*)(er + 16 * cb + 16);
            STEP(q1, e1, e2, e3, e0);
            e1 = *(const float4*)(er + 16 * cb + 20);
            STEP(q2, e2, e3, e0, e1);
            e2 = *(const float4*)(er + 16 * cb + 24);
            STEP(q3, e3, e0, e1, e2);
            e3 = *(const float4*)(er + 16 * cb + 28);
        }
    }
    // pack 12 f32 -> 6 uints (bf16 pairs); uint offset = (row*96+x0)/2, 8B-aligned
    unsigned* outp = (unsigned*)part +
        ((size_t)(ic * 16 + b) * 6144 + (size_t)(o0 + orow) * 96 + x0) / 2;
    *(uint2*)(outp)     = make_uint2(bf16pack(accA.x, accA.y), bf16pack(accA.z, accA.w));
    *(uint2*)(outp + 2) = make_uint2(bf16pack(accB.x, accB.y), bf16pack(accB.z, accB.w));
    *(uint2*)(outp + 4) = make_uint2(bf16pack(accC.x, accC.y), bf16pack(accC.z, accC.w));
}

// ---------------------------------------------------------------------------
// cooperative matvec: 4 lanes per output row, float4 loads, shuffle reduce.
// ---------------------------------------------------------------------------
__device__ __forceinline__ void matvec4(int g, int q, int nout, int nk,
    const float* __restrict__ W, int ldw, const float* __restrict__ bias,
    const float* __restrict__ xv, float* __restrict__ y)
{
    for (int j = g; j < nout; j += 64) {
        const float* wr = W + (size_t)j * ldw;
        float s = 0.f;
        for (int m = q; m < nk / 4; m += 4) {
            float4 wq = *(const float4*)(wr + 4 * m);
            s += wq.x * xv[4 * m] + wq.y * xv[4 * m + 1]
               + wq.z * xv[4 * m + 2] + wq.w * xv[4 * m + 3];
        }
        s += __shfl_xor(s, 1);
        s += __shfl_xor(s, 2);
        if (q == 0) y[j] = s + bias[j];
    }
}

// ---------------------------------------------------------------------------
// K1: fused attn1 + GRU + attn2 + pre-output, one block (256 thr) per b.
// ---------------------------------------------------------------------------
__global__ __launch_bounds__(256) void k_fused(
    const float* __restrict__ enc, const int* __restrict__ ids,
    const float* __restrict__ hidden, const float* __restrict__ coverage,
    const float* __restrict__ emb,
    const float* __restrict__ W_dec, const float* __restrict__ b_dec,
    const float* __restrict__ attn_b,
    const float* __restrict__ cvgw47, const float* __restrict__ cvg_b,
    const float* __restrict__ vvec,
    const float* __restrict__ W_new, const float* __restrict__ b_new,
    const float* __restrict__ w_ih, const float* __restrict__ w_hh,
    const float* __restrict__ b_ih, const float* __restrict__ b_hh,
    const float* __restrict__ W_pre, const float* __restrict__ b_pre,
    const unsigned short* __restrict__ part, float* __restrict__ oG,
    float* __restrict__ out_hidden, float* __restrict__ out_ctx2,
    float* __restrict__ out_aw2, float* __restrict__ out_cov2)
{
    int b = blockIdx.x, t = threadIdx.x;
    int g = t >> 2, q = t & 3;

    __shared__ __align__(16) float efS[ENC * HH];    // summed enc_feat slice
    __shared__ __align__(16) float encS[ENC * HH];   // enc slice
    __shared__ float hS[HH], vS[HH], decS[HH], ctxS[HH], xS[HH], h2S[HH], ctx2S[HH];
    __shared__ float covS[ENC], cvgS[ENC], sS[ENC], awS[ENC];
    __shared__ float embS[EE];
    __shared__ __align__(16) float xcatS[EE + HH];
    __shared__ float giS[3 * HH], ghS[3 * HH];

    {   // 16-way bf16 partial sum: 768 uint4 (8 bf16 each) per partial
        const uint4* part4 = (const uint4*)part;
        for (int f = t; f < 768; f += 256) {
            float s0=0.f,s1=0.f,s2=0.f,s3=0.f,s4=0.f,s5=0.f,s6=0.f,s7=0.f;
            #pragma unroll
            for (int ic = 0; ic < 16; ++ic) {
                uint4 p = part4[(size_t)(ic * 16 + b) * 768 + f];
                s0 += BF_LO(p.x); s1 += BF_HI(p.x);
                s2 += BF_LO(p.y); s3 += BF_HI(p.y);
                s4 += BF_LO(p.z); s5 += BF_HI(p.z);
                s6 += BF_LO(p.w); s7 += BF_HI(p.w);
            }
            float4* d = (float4*)&efS[8 * f];
            d[0] = make_float4(s0, s1, s2, s3);
            d[1] = make_float4(s4, s5, s6, s7);
        }
        const float4* enc4 = (const float4*)(enc + (size_t)b * ENC * HH);
        float4* encS4 = (float4*)encS;
        for (int f = t; f < (ENC * HH) / 4; f += 256) encS4[f] = enc4[f];
    }
    if (t < HH) { hS[t] = hidden[b * HH + t]; vS[t] = vvec[b * HH + t]; }
    if (t >= 96 && t < 160) covS[t - 96] = coverage[b * ENC + (t - 96)];
    if (t >= 128 && t < 256) embS[t - 128] = emb[(size_t)ids[b] * EE + (t - 128)];
    __syncthreads();

    // ======== attention pass 1 ========
    matvec4(g, q, HH, HH, W_dec, HH, b_dec, hS, decS);
    matvec4(g, q, ENC, ENC, cvgw47, ENC, cvg_b, covS, cvgS);
    __syncthreads();
    {
        int e = g;
        float base = attn_b[e] + cvgS[e];
        const float* efr = &efS[e * HH];
        float s = 0.f;
        for (int m = q; m < 24; m += 4) {
            #pragma unroll
            for (int u = 0; u < 4; ++u) {
                int xx = 4 * m + u;
                s += tanh_fast(efr[xx] + decS[xx] + base) * vS[xx];
            }
        }
        s += __shfl_xor(s, 1); s += __shfl_xor(s, 2);
        if (q == 0) sS[e] = s;
    }
    __syncthreads();
    if (t < ENC) {
        float m = -1e30f;
        for (int j = 0; j < ENC; ++j) m = fmaxf(m, sS[j]);
        float sum = 0.f;
        for (int j = 0; j < ENC; ++j) sum += __expf(sS[j] - m);
        float aw = __expf(sS[t] - m) / sum;
        awS[t] = aw;
        covS[t] += aw;
    }
    __syncthreads();
    if (t < HH) {
        float c = 0.f;
        for (int o = 0; o < ENC; ++o) c += awS[o] * encS[o * HH + t];
        ctxS[t] = c;
        xcatS[EE + t] = c;
    }
    if (t >= 128 && t < 256) xcatS[t - 128] = embS[t - 128];
    __syncthreads();

    // ======== x = W_new @ [emb; ctx1] + b_new ========
    matvec4(g, q, HH, EE + HH, W_new, EE + HH, b_new, xcatS, xS);
    __syncthreads();

    // ======== GRU (gate order r, z, n) ========
    matvec4(g, q, 3 * HH, HH, w_ih, HH, b_ih, xS, giS);
    matvec4(g, q, 3 * HH, HH, w_hh, HH, b_hh, hS, ghS);
    __syncthreads();
    if (t < HH) {
        float r = sigmoid_fast(giS[t] + ghS[t]);
        float z = sigmoid_fast(giS[HH + t] + ghS[HH + t]);
        float n = tanh_fast(giS[2 * HH + t] + r * ghS[2 * HH + t]);
        float hn = (1.f - z) * n + z * hS[t];
        h2S[t] = hn;
        out_hidden[b * HH + t] = hn;
    }
    __syncthreads();

    // ======== attention pass 2 (covS now = cov1) ========
    matvec4(g, q, HH, HH, W_dec, HH, b_dec, h2S, decS);
    matvec4(g, q, ENC, ENC, cvgw47, ENC, cvg_b, covS, cvgS);
    __syncthreads();
    {
        int e = g;
        float base = attn_b[e] + cvgS[e];
        const float* efr = &efS[e * HH];
        float s = 0.f;
        for (int m = q; m < 24; m += 4) {
            #pragma unroll
            for (int u = 0; u < 4; ++u) {
                int xx = 4 * m + u;
                s += tanh_fast(efr[xx] + decS[xx] + base) * vS[xx];
            }
        }
        s += __shfl_xor(s, 1); s += __shfl_xor(s, 2);
        if (q == 0) sS[e] = s;
    }
    __syncthreads();
    if (t < ENC) {
        float m = -1e30f;
        for (int j = 0; j < ENC; ++j) m = fmaxf(m, sS[j]);
        float sum = 0.f;
        for (int j = 0; j < ENC; ++j) sum += __expf(sS[j] - m);
        float aw = __expf(sS[t] - m) / sum;
        awS[t] = aw;
        covS[t] += aw;
        out_aw2[b * ENC + t]  = aw;
        out_cov2[b * ENC + t] = covS[t];
    }
    __syncthreads();
    if (t < HH) {
        float c = 0.f;
        for (int o = 0; o < ENC; ++o) c += awS[o] * encS[o * HH + t];
        ctx2S[t] = c;
        out_ctx2[b * HH + t] = c;
        xcatS[t] = h2S[t];
        xcatS[HH + t] = c;
    }
    __syncthreads();

    // ======== o = tanh(W_pre @ [h2; ctx2] + b_pre) ========
    for (int j = g; j < HH; j += 64) {
        const float* wr = W_pre + (size_t)j * (2 * HH);
        float s = 0.f;
        for (int m = q; m < (2 * HH) / 4; m += 4) {
            float4 wq = *(const float4*)(wr + 4 * m);
            s += wq.x * xcatS[4 * m] + wq.y * xcatS[4 * m + 1]
               + wq.z * xcatS[4 * m + 2] + wq.w * xcatS[4 * m + 3];
        }
        s += __shfl_xor(s, 1); s += __shfl_xor(s, 2);
        if (q == 0) oG[b * HH + j] = tanh_fast(s + b_pre[j]);
    }
}

// ---------------------------------------------------------------------------
// K2: logits + per-block softmax partials. 250 blocks x 128 thr (2 waves).
// Each thread owns one v and all 16 b. After the store, wave-shuffle
// reductions produce per-(block,b) max and expsum -> pmax/psum.
// ---------------------------------------------------------------------------
__global__ __launch_bounds__(128) void k_logits(
    const float* __restrict__ oG, const float* __restrict__ W_out,
    const float* __restrict__ b_out, float* __restrict__ logits,
    float* __restrict__ pmax, float* __restrict__ psum)
{
    __shared__ __align__(16) float oS[BB * HH];
    for (int i = threadIdx.x; i < BB * HH; i += 128) oS[i] = oG[i];
    __syncthreads();

    int t = threadIdx.x;
    int v = blockIdx.x * 128 + t;   // 250*128 == 32000
    const float4* row = (const float4*)(W_out + (size_t)v * HH);
    float acc[BB];
    #pragma unroll
    for (int b = 0; b < BB; ++b) acc[b] = 0.f;

    #pragma unroll 6
    for (int c = 0; c < HH / 4; ++c) {
        float4 qv = row[c];
        #pragma unroll
        for (int b = 0; b < BB; ++b) {
            const float4 o0 = *(const float4*)&oS[b * HH + c * 4];
            acc[b] += qv.x * o0.x + qv.y * o0.y + qv.z * o0.z + qv.w * o0.w;
        }
    }
    float bo = b_out[v];
    #pragma unroll
    for (int b = 0; b < BB; ++b) {
        acc[b] += bo;
        logits[b * VV + v] = acc[b];
    }

    // per-(block,b) max & expsum
    __shared__ float smx[2][BB], sms[2][BB];
    int wv = t >> 6, ln = t & 63;
    #pragma unroll
    for (int b = 0; b < BB; ++b) {
        float m = acc[b];
        m = fmaxf(m, __shfl_xor(m, 1));
        m = fmaxf(m, __shfl_xor(m, 2));
        m = fmaxf(m, __shfl_xor(m, 4));
        m = fmaxf(m, __shfl_xor(m, 8));
        m = fmaxf(m, __shfl_xor(m, 16));
        m = fmaxf(m, __shfl_xor(m, 32));
        if (ln == 0) smx[wv][b] = m;
    }
    __syncthreads();
    #pragma unroll
    for (int b = 0; b < BB; ++b) {
        float Mb = fmaxf(smx[0][b], smx[1][b]);
        float s = __expf(acc[b] - Mb);
        s += __shfl_xor(s, 1);
        s += __shfl_xor(s, 2);
        s += __shfl_xor(s, 4);
        s += __shfl_xor(s, 8);
        s += __shfl_xor(s, 16);
        s += __shfl_xor(s, 32);
        if (ln == 0) sms[wv][b] = s;
    }
    __syncthreads();
    if (t < BB) {
        pmax[blockIdx.x * BB + t] = fmaxf(smx[0][t], smx[1][t]);
        psum[blockIdx.x * BB + t] = sms[0][t] + sms[1][t];
    }
}

// ---------------------------------------------------------------------------
// K3: finalize log_softmax. 256 blocks x 256 thr: blk = b*16 + slice.
// Each block reduces the 250 (m,S) partials for its row (redundant x16,
// ~2 KB from L2), then subtracts logZ over its 2000-element slice.
// ---------------------------------------------------------------------------
__global__ __launch_bounds__(256) void k_lsm(
    float* __restrict__ logits,
    const float* __restrict__ pmax, const float* __restrict__ psum)
{
    int blk = blockIdx.x;
    int b = blk >> 4, s = blk & 15;
    int t = threadIdx.x;
    __shared__ float red[256];

    float mt = (t < 250) ? pmax[t * BB + b] : -1e30f;
    red[t] = mt;
    __syncthreads();
    for (int o = 128; o > 0; o >>= 1) {
        if (t < o) red[t] = fmaxf(red[t], red[t + o]);
        __syncthreads();
    }
    float M = red[0];
    __syncthreads();
    float st = (t < 250) ? psum[t * BB + b] * __expf(mt - M) : 0.f;
    red[t] = st;
    __syncthreads();
    for (int o = 128; o > 0; o >>= 1) {
        if (t < o) red[t] += red[t + o];
        __syncthreads();
    }
    float logZ = M + logf(red[0]);

    float4* row4 = (float4*)(logits + (size_t)b * VV);
    for (int k = s * 500 + t; k < (s + 1) * 500; k += 256) {
        float4 c = row4[k];
        c.x -= logZ; c.y -= logZ; c.z -= logZ; c.w -= logZ;
        row4[k] = c;
    }
}

// ---------------------------------------------------------------------------
extern "C" void kernel_launch(void* const* d_in, const int* in_sizes, int n_in,
                              void* d_out, int out_size, void* d_ws, size_t ws_size,
                              hipStream_t stream) {
    const float* enc    = (const float*)d_in[0];
    const int*   ids    = (const int*)d_in[1];
    const float* hidden = (const float*)d_in[2];
    const float* cover  = (const float*)d_in[3];
    const float* emb    = (const float*)d_in[4];
    const float* W_dec  = (const float*)d_in[5];
    const float* b_dec  = (const float*)d_in[6];
    const float* attn_w = (const float*)d_in[7];
    const float* attn_b = (const float*)d_in[8];
    const float* cvg_w  = (const float*)d_in[9];
    const float* cvg_b  = (const float*)d_in[10];
    const float* vvec   = (const float*)d_in[11];
    const float* W_new  = (const float*)d_in[12];
    const float* b_new  = (const float*)d_in[13];
    const float* w_ih   = (const float*)d_in[14];
    const float* w_hh   = (const float*)d_in[15];
    const float* b_ih   = (const float*)d_in[16];
    const float* b_hh   = (const float*)d_in[17];
    const float* W_pre  = (const float*)d_in[18];
    const float* b_pre  = (const float*)d_in[19];
    const float* W_out  = (const float*)d_in[20];
    const float* b_out  = (const float*)d_in[21];

    // ws (floats): [0..1536) oG | [1536..5632) cvgw47 | [5632..9632) pmax
    //              [9632..13632) psum | [13632..) part (bf16, 3.1 MB)
    float* wsf    = (float*)d_ws;
    float* oG     = wsf;
    float* cvgw47 = wsf + 1536;
    float* pmax   = wsf + 5632;
    float* psum   = wsf + 9632;
    unsigned short* part = (unsigned short*)(wsf + 13632);  // 16*16*64*96 bf16

    float* out        = (float*)d_out;
    float* out_logp   = out;               // 512000 (logits in place)
    float* out_hidden = out + 512000;
    float* out_ctx2   = out + 513536;
    float* out_aw2    = out + 515072;
    float* out_cov2   = out + 516096;

    k_encfeat<<<1024, 128, 0, stream>>>(enc, attn_w, cvg_w, part, cvgw47);
    k_fused<<<16, 256, 0, stream>>>(enc, ids, hidden, cover, emb, W_dec, b_dec,
                                    attn_b, cvgw47, cvg_b, vvec, W_new, b_new,
                                    w_ih, w_hh, b_ih, b_hh, W_pre, b_pre,
                                    part, oG,
                                    out_hidden, out_ctx2, out_aw2, out_cov2);
    k_logits<<<250, 128, 0, stream>>>(oG, W_out, b_out, out_logp, pmax, psum);
    k_lsm<<<256, 256, 0, stream>>>(out_logp, pmax, psum);
}